// Round 10
// baseline (509.031 us; speedup 1.0000x reference)
//
#include <hip/hip_runtime.h>
#include <stdint.h>

#define Mm 8192
#define Dd 1024

typedef unsigned short u16;
typedef __attribute__((ext_vector_type(8))) short bf16x8;
typedef __attribute__((ext_vector_type(4))) float f32x4;
typedef __attribute__((ext_vector_type(4))) u16 u16x4;

__device__ __forceinline__ u16 f2bf(float f) {
  union { float f; uint32_t u; } c; c.f = f;
  uint32_t u = c.u;
  return (u16)((u + 0x7fffu + ((u >> 16) & 1u)) >> 16);
}

__device__ __forceinline__ float EXP2(float x) {
#if __has_builtin(__builtin_amdgcn_exp2f)
  return __builtin_amdgcn_exp2f(x);
#else
  return exp2f(x);
#endif
}

__device__ __forceinline__ float LOG2(float x) {
#if __has_builtin(__builtin_amdgcn_logf)
  return __builtin_amdgcn_logf(x);
#else
  return log2f(x);
#endif
}

__device__ __forceinline__ uint32_t cvtpk(float a, float b) {
  uint32_t r;
  asm("v_cvt_pk_bf16_f32 %0, %1, %2" : "=v"(r) : "v"(a), "v"(b));
  return r;
}

__device__ __forceinline__ void gll16(const void* g, void* l) {
  __builtin_amdgcn_global_load_lds((const __attribute__((address_space(1))) void*)g,
                                   (__attribute__((address_space(3))) void*)l, 16, 0, 0);
}

// ---------------- fp32 -> bf16 convert ----------------
__global__ void cvt_all(const float* __restrict__ x, const float* __restrict__ wq,
                        const float* __restrict__ wk, const float* __restrict__ wv,
                        const float* __restrict__ wo, u16* __restrict__ out) {
  const int xn4 = 2097152, wn4 = 262144;
  const int total = xn4 + 4 * wn4;
  int i = blockIdx.x * blockDim.x + threadIdx.x;
  int stride = gridDim.x * blockDim.x;
  for (; i < total; i += stride) {
    const float* src; int off;
    if (i < xn4) { src = x; off = i; }
    else {
      int j = i - xn4; int wsel = j >> 18; off = j & (wn4 - 1);
      src = (wsel == 0) ? wq : (wsel == 1) ? wk : (wsel == 2) ? wv : wo;
    }
    float4 v = ((const float4*)src)[off];
    u16x4 o;
    o.x = f2bf(v.x); o.y = f2bf(v.y); o.z = f2bf(v.z); o.w = f2bf(v.w);
    ((u16x4*)out)[i] = o;
  }
}

// ---------------- fused QKV GEMM ----------------
__global__ __launch_bounds__(256) void gemm_qkv(
    const u16* __restrict__ A, const u16* __restrict__ Wt,
    const float* __restrict__ bq, const float* __restrict__ bk, const float* __restrict__ bv,
    u16* __restrict__ Qo, u16* __restrict__ Ko, u16* __restrict__ Vo, float qscale)
{
  __shared__ u16 As[128 * 32];
  __shared__ u16 Bs[128 * 32];
  const int K = 1024, tiles_n = 24;
  int nwg = 64 * 24;
  int bid = blockIdx.x;
  { int q = nwg >> 3; bid = (bid & 7) * q + (bid >> 3); }
  int tm = bid / tiles_n, tn = bid % tiles_n;
  int tid = threadIdx.x;
  int wid = tid >> 6, lane = tid & 63;
  int wr = wid >> 1, wc = wid & 1;

  f32x4 acc[4][4] = {};
  int a_row = wr * 64 + (lane & 15);
  int b_row = wc * 64 + (lane & 15);
  int frag_k = (lane >> 4) * 8;

  const u16* ga0 = A + (size_t)(tm * 128 + wid * 32 + (lane >> 2)) * K + (lane & 3) * 8;
  const u16* ga1 = ga0 + (size_t)16 * K;
  const u16* gb0 = Wt + (size_t)(tn * 128 + wid * 32 + (lane >> 2)) * K + (lane & 3) * 8;
  const u16* gb1 = gb0 + (size_t)16 * K;
  u16* lA0 = As + wid * 1024;
  u16* lA1 = As + wid * 1024 + 512;
  u16* lB0 = Bs + wid * 1024;
  u16* lB1 = Bs + wid * 1024 + 512;

  for (int kt = 0; kt < K; kt += 32) {
    gll16(ga0 + kt, lA0);
    gll16(ga1 + kt, lA1);
    gll16(gb0 + kt, lB0);
    gll16(gb1 + kt, lB1);
    __syncthreads();
    bf16x8 af[4], bfr[4];
#pragma unroll
    for (int i = 0; i < 4; i++)
      af[i] = *(const bf16x8*)(As + (a_row + i * 16) * 32 + frag_k);
#pragma unroll
    for (int i = 0; i < 4; i++)
      bfr[i] = *(const bf16x8*)(Bs + (b_row + i * 16) * 32 + frag_k);
#pragma unroll
    for (int i = 0; i < 4; i++)
#pragma unroll
      for (int j = 0; j < 4; j++)
        acc[i][j] = __builtin_amdgcn_mfma_f32_16x16x32_bf16(af[i], bfr[j], acc[i][j], 0, 0, 0);
    __syncthreads();
  }

#pragma unroll
  for (int i = 0; i < 4; i++) {
#pragma unroll
    for (int j = 0; j < 4; j++) {
      int col = tn * 128 + wc * 64 + j * 16 + (lane & 15);
      int wsel = col >> 10, c10 = col & 1023;
      int h = c10 >> 6, hd = c10 & 63;
      float bvv = (wsel == 0 ? bq : wsel == 1 ? bk : bv)[c10];
      int row0 = tm * 128 + wr * 64 + i * 16 + (lane >> 4) * 4;
      int b_ = row0 >> 11, s0 = row0 & 2047;
      if (wsel == 2) {
        u16x4 o;
#pragma unroll
        for (int r = 0; r < 4; r++) o[r] = f2bf(acc[i][j][r] + bvv);
        *(u16x4*)&Vo[((size_t)(b_ * 16 + h) * 64 + hd) * 2048 + s0] = o;
      } else {
        u16* dst = (wsel == 0) ? Qo : Ko;
        float sc = (wsel == 0) ? qscale : 1.0f;
#pragma unroll
        for (int r = 0; r < 4; r++)
          dst[(((size_t)(b_ * 16 + h) * 2048 + (s0 + r)) << 6) + hd] = f2bf((acc[i][j][r] + bvv) * sc);
      }
    }
  }
}

// ---------------- out GEMM: fp32 [M,N] ----------------
__global__ __launch_bounds__(256) void gemm_out(
    const u16* __restrict__ A, const u16* __restrict__ Bt,
    const float* __restrict__ bias, float* __restrict__ out,
    int M, int N, int K)
{
  __shared__ u16 As[128 * 32];
  __shared__ u16 Bs[128 * 32];
  int tiles_n = N >> 7;
  int nwg = (M >> 7) * tiles_n;
  int bid = blockIdx.x;
  { int q = nwg >> 3; bid = (bid & 7) * q + (bid >> 3); }
  int tm = bid / tiles_n, tn = bid % tiles_n;
  int tid = threadIdx.x;
  int wid = tid >> 6, lane = tid & 63;
  int wr = wid >> 1, wc = wid & 1;

  f32x4 acc[4][4] = {};
  int a_row = wr * 64 + (lane & 15);
  int b_row = wc * 64 + (lane & 15);
  int frag_k = (lane >> 4) * 8;

  const u16* ga0 = A + (size_t)(tm * 128 + wid * 32 + (lane >> 2)) * K + (lane & 3) * 8;
  const u16* ga1 = ga0 + (size_t)16 * K;
  const u16* gb0 = Bt + (size_t)(tn * 128 + wid * 32 + (lane >> 2)) * K + (lane & 3) * 8;
  const u16* gb1 = gb0 + (size_t)16 * K;
  u16* lA0 = As + wid * 1024;
  u16* lA1 = As + wid * 1024 + 512;
  u16* lB0 = Bs + wid * 1024;
  u16* lB1 = Bs + wid * 1024 + 512;

  for (int kt = 0; kt < K; kt += 32) {
    gll16(ga0 + kt, lA0);
    gll16(ga1 + kt, lA1);
    gll16(gb0 + kt, lB0);
    gll16(gb1 + kt, lB1);
    __syncthreads();
    bf16x8 af[4], bfr[4];
#pragma unroll
    for (int i = 0; i < 4; i++)
      af[i] = *(const bf16x8*)(As + (a_row + i * 16) * 32 + frag_k);
#pragma unroll
    for (int i = 0; i < 4; i++)
      bfr[i] = *(const bf16x8*)(Bs + (b_row + i * 16) * 32 + frag_k);
#pragma unroll
    for (int i = 0; i < 4; i++)
#pragma unroll
      for (int j = 0; j < 4; j++)
        acc[i][j] = __builtin_amdgcn_mfma_f32_16x16x32_bf16(af[i], bfr[j], acc[i][j], 0, 0, 0);
    __syncthreads();
  }

#pragma unroll
  for (int i = 0; i < 4; i++)
#pragma unroll
    for (int j = 0; j < 4; j++) {
      int col = tn * 128 + wc * 64 + j * 16 + (lane & 15);
      float bv = bias[col];
#pragma unroll
      for (int r = 0; r < 4; r++) {
        int row = tm * 128 + wr * 64 + i * 16 + (lane >> 4) * 4 + r;
        out[(size_t)row * N + col] = acc[i][j][r] + bv;
      }
    }
}

// ---------------- attn pass 1: row log-sums (K only, 32KB LDS, 4 blocks/CU) ----------------
// grid 1024 (bh x qt128), 512 threads. Single barrier/iter; nbuf=4, dist=2.
__global__ __launch_bounds__(512, 8) void attn_pass1(
    const u16* __restrict__ Qb, const u16* __restrict__ Kb, float* __restrict__ lrbuf)
{
  __shared__ u16 Ks[4][4096];
  int bid = blockIdx.x;
  int swz = (bid & 7) * 128 + (bid >> 3);
  int bh = swz >> 4, qt = swz & 15;
  int tid = threadIdx.x, w = tid >> 6, lane = tid & 63;
  int g = lane >> 4, l15 = lane & 15;

  const u16* Qg = Qb + ((size_t)bh * 2048 + qt * 128) * 64;
  const u16* Kg = Kb + (size_t)bh * 2048 * 64;
  int qloc = w * 16 + l15;
  bf16x8 aq0 = *(const bf16x8*)(Qg + (size_t)qloc * 64 + g * 8);
  bf16x8 aq1 = *(const bf16x8*)(Qg + (size_t)qloc * 64 + 32 + g * 8);

  int srow = w * 8 + (lane >> 3);
  int schunk = (lane & 7) ^ (lane >> 3);
  const u16* Ksrc = Kg + (size_t)srow * 64 + schunk * 8;

  float ls0 = 0.f, ls1 = 0.f, ls2 = 0.f, ls3 = 0.f;
  gll16(Ksrc, (char*)Ks[0] + w * 1024);
  gll16(Ksrc + 4096, (char*)Ks[1] + w * 1024);
  for (int it = 0; it < 32; ++it) {
    if (it < 30) gll16(Ksrc + (size_t)(it + 2) * 4096, (char*)Ks[(it + 2) & 3] + w * 1024);
    if (it < 30)       asm volatile("s_waitcnt vmcnt(2)" ::: "memory");
    else if (it == 30) asm volatile("s_waitcnt vmcnt(1)" ::: "memory");
    else               asm volatile("s_waitcnt vmcnt(0)" ::: "memory");
    __builtin_amdgcn_s_barrier();
    const char* Kbase = (const char*)Ks[it & 3];
    f32x4 s[4] = {};
    __builtin_amdgcn_s_setprio(1);
#pragma unroll
    for (int t = 0; t < 4; t++) {
      int kr = t * 16 + l15;
      int x = (kr & 7) << 4;
      bf16x8 k0 = *(const bf16x8*)(Kbase + kr * 128 + ((g * 16) ^ x));
      bf16x8 k1 = *(const bf16x8*)(Kbase + kr * 128 + ((64 + g * 16) ^ x));
      s[t] = __builtin_amdgcn_mfma_f32_16x16x32_bf16(k0, aq0, s[t], 0, 0, 0);
      s[t] = __builtin_amdgcn_mfma_f32_16x16x32_bf16(k1, aq1, s[t], 0, 0, 0);
    }
    __builtin_amdgcn_s_setprio(0);
#pragma unroll
    for (int r = 0; r < 4; r++) {
      ls0 += EXP2(s[0][r]); ls1 += EXP2(s[1][r]);
      ls2 += EXP2(s[2][r]); ls3 += EXP2(s[3][r]);
    }
  }
  float lsum = (ls0 + ls1) + (ls2 + ls3);
  lsum += __shfl_xor(lsum, 16);
  lsum += __shfl_xor(lsum, 32);
  if (!g) lrbuf[(size_t)bh * 2048 + qt * 128 + qloc] = -LOG2(lsum);
}

// ---------------- attn pass 2: attn write + PV (80KB LDS, 2 blocks/CU) ----------------
// grid 1024, 512 threads. Single barrier/iter; nbuf=4, dist=2.
__global__ __launch_bounds__(512, 4) void attn_pass2(
    const u16* __restrict__ Qb, const u16* __restrict__ Kb,
    const u16* __restrict__ Vtb, const float* __restrict__ lrbuf,
    float* __restrict__ attn_out, u16* __restrict__ ctxb)
{
  __shared__ u16 Ks[4][4096];
  __shared__ u16 Vs[4][4096];
  __shared__ u16 Ps[8192];

  int bid = blockIdx.x;
  int swz = (bid & 7) * 128 + (bid >> 3);
  int bh = swz >> 4, qt = swz & 15;
  int tid = threadIdx.x, w = tid >> 6, lane = tid & 63;
  int g = lane >> 4, l15 = lane & 15;

  const u16* Qg = Qb + ((size_t)bh * 2048 + qt * 128) * 64;
  const u16* Kg = Kb + (size_t)bh * 2048 * 64;
  const u16* Vg = Vtb + (size_t)bh * 64 * 2048;
  float* Ag = attn_out + ((size_t)bh * 2048 + qt * 128) * 2048;

  int qloc = w * 16 + l15;
  bf16x8 aq0 = *(const bf16x8*)(Qg + (size_t)qloc * 64 + g * 8);
  bf16x8 aq1 = *(const bf16x8*)(Qg + (size_t)qloc * 64 + 32 + g * 8);
  float lr2 = lrbuf[(size_t)bh * 2048 + qt * 128 + qloc];

  int srow = w * 8 + (lane >> 3);
  int schunk = (lane & 7) ^ (lane >> 3);
  const u16* Ksrc = Kg + (size_t)srow * 64 + schunk * 8;
  const u16* Vsrc = Vg + (size_t)srow * 2048 + schunk * 8;

  int xq = (qloc & 7) << 4;
  char* Pb = (char*)Ps + qloc * 128;

  f32x4 ctx[4] = {};
#pragma unroll
  for (int p = 0; p < 2; p++) {
    gll16(Ksrc + (size_t)p * 4096, (char*)Ks[p] + w * 1024);
    gll16(Vsrc + (size_t)p * 64,  (char*)Vs[p] + w * 1024);
  }
  for (int it = 0; it < 32; ++it) {
    if (it < 30) {
      gll16(Ksrc + (size_t)(it + 2) * 4096, (char*)Ks[(it + 2) & 3] + w * 1024);
      gll16(Vsrc + (size_t)(it + 2) * 64,  (char*)Vs[(it + 2) & 3] + w * 1024);
    }
    if (it == 0)       asm volatile("s_waitcnt vmcnt(4)" ::: "memory");
    else if (it == 1)  asm volatile("s_waitcnt vmcnt(8)" ::: "memory");
    else if (it < 30)  asm volatile("s_waitcnt vmcnt(12)" ::: "memory");
    else if (it == 30) asm volatile("s_waitcnt vmcnt(10)" ::: "memory");
    else               asm volatile("s_waitcnt vmcnt(8)" ::: "memory");
    __builtin_amdgcn_s_barrier();
    const char* Kbase = (const char*)Ks[it & 3];
    const char* Vbase = (const char*)Vs[it & 3];
    f32x4 s[4] = {};
    __builtin_amdgcn_s_setprio(1);
#pragma unroll
    for (int t = 0; t < 4; t++) {
      int kr = t * 16 + l15;
      int x = (kr & 7) << 4;
      bf16x8 k0 = *(const bf16x8*)(Kbase + kr * 128 + ((g * 16) ^ x));
      bf16x8 k1 = *(const bf16x8*)(Kbase + kr * 128 + ((64 + g * 16) ^ x));
      s[t] = __builtin_amdgcn_mfma_f32_16x16x32_bf16(k0, aq0, s[t], 0, 0, 0);
      s[t] = __builtin_amdgcn_mfma_f32_16x16x32_bf16(k1, aq1, s[t], 0, 0, 0);
    }
    __builtin_amdgcn_s_setprio(0);
    float* Arow = Ag + (size_t)qloc * 2048 + it * 64 + g * 4;
#pragma unroll
    for (int t = 0; t < 4; t++) {
      f32x4 p;
#pragma unroll
      for (int r = 0; r < 4; r++) p[r] = EXP2(s[t][r] + lr2);
      __builtin_nontemporal_store(p, (f32x4*)(Arow + t * 16));
      uint2 pk;
      pk.x = cvtpk(p[0], p[1]);
      pk.y = cvtpk(p[2], p[3]);
      *(uint2*)(Pb + ((t * 32 + g * 8) ^ xq)) = pk;
    }
    __builtin_amdgcn_s_setprio(1);
#pragma unroll
    for (int kk = 0; kk < 2; kk++) {
      bf16x8 ap = *(const bf16x8*)(Pb + ((kk * 64 + g * 16) ^ xq));
#pragma unroll
      for (int t = 0; t < 4; t++) {
        int dr = t * 16 + l15;
        bf16x8 bv = *(const bf16x8*)(Vbase + dr * 128 + ((kk * 64 + g * 16) ^ ((dr & 7) << 4)));
        ctx[t] = __builtin_amdgcn_mfma_f32_16x16x32_bf16(ap, bv, ctx[t], 0, 0, 0);
      }
    }
    __builtin_amdgcn_s_setprio(0);
  }

  int b_ = bh >> 4, h = bh & 15;
#pragma unroll
  for (int t = 0; t < 4; t++)
#pragma unroll
    for (int r = 0; r < 4; r++) {
      int qg = qt * 128 + w * 16 + g * 4 + r;
      int col = h * 64 + t * 16 + l15;
      ctxb[((size_t)b_ * 2048 + qg) * 1024 + col] = f2bf(ctx[t][r]);
    }
}

// ---------------- launch ----------------
extern "C" void kernel_launch(void* const* d_in, const int* in_sizes, int n_in,
                              void* d_out, int out_size, void* d_ws, size_t ws_size,
                              hipStream_t stream) {
  const float* x  = (const float*)d_in[0];
  const float* Wq = (const float*)d_in[1];
  const float* bq = (const float*)d_in[2];
  const float* Wk = (const float*)d_in[3];
  const float* bk = (const float*)d_in[4];
  const float* Wv = (const float*)d_in[5];
  const float* bv = (const float*)d_in[6];
  const float* Wo = (const float*)d_in[7];
  const float* bo = (const float*)d_in[8];

  u16* xb   = (u16*)d_ws;
  u16* Wqb  = xb + (size_t)Mm * Dd;
  u16* Wkb  = Wqb + (size_t)Dd * Dd;
  u16* Wvb  = Wkb + (size_t)Dd * Dd;
  u16* Wob  = Wvb + (size_t)Dd * Dd;
  u16* Qb   = Wob + (size_t)Dd * Dd;
  u16* Kbuf = Qb + (size_t)Mm * Dd;
  u16* Vtb  = Kbuf + (size_t)Mm * Dd;
  u16* ctxb = Vtb + (size_t)Mm * Dd;
  float* lrbuf = (float*)(ctxb + (size_t)Mm * Dd);

  float* out_f = (float*)d_out;
  float* attn_o = out_f + (size_t)Mm * Dd;

  cvt_all<<<2048, 256, 0, stream>>>(x, Wq, Wk, Wv, Wo, xb);

  const float qscale = 0.125f * 1.44269504088896340736f;  // 1/sqrt(64) * log2(e)
  gemm_qkv<<<1536, 256, 0, stream>>>(xb, Wqb, bq, bk, bv, Qb, Kbuf, Vtb, qscale);
  attn_pass1<<<1024, 512, 0, stream>>>(Qb, Kbuf, lrbuf);
  attn_pass2<<<1024, 512, 0, stream>>>(Qb, Kbuf, Vtb, lrbuf, attn_o, ctxb);
  gemm_out<<<512, 256, 0, stream>>>(ctxb, Wob, bo, out_f, Mm, Dd, Dd);
}

// Round 11
// 436.270 us; speedup vs baseline: 1.1668x; 1.1668x over previous
//
#include <hip/hip_runtime.h>
#include <stdint.h>

#define Mm 8192
#define Dd 1024

typedef unsigned short u16;
typedef __attribute__((ext_vector_type(8))) short bf16x8;
typedef __attribute__((ext_vector_type(4))) float f32x4;
typedef __attribute__((ext_vector_type(4))) u16 u16x4;

__device__ __forceinline__ u16 f2bf(float f) {
  union { float f; uint32_t u; } c; c.f = f;
  uint32_t u = c.u;
  return (u16)((u + 0x7fffu + ((u >> 16) & 1u)) >> 16);
}

__device__ __forceinline__ float EXP2(float x) {
#if __has_builtin(__builtin_amdgcn_exp2f)
  return __builtin_amdgcn_exp2f(x);
#else
  return exp2f(x);
#endif
}

__device__ __forceinline__ float LOG2(float x) {
#if __has_builtin(__builtin_amdgcn_logf)
  return __builtin_amdgcn_logf(x);
#else
  return log2f(x);
#endif
}

__device__ __forceinline__ uint32_t cvtpk(float a, float b) {
  uint32_t r;
  asm("v_cvt_pk_bf16_f32 %0, %1, %2" : "=v"(r) : "v"(a), "v"(b));
  return r;
}

__device__ __forceinline__ void gll16(const void* g, void* l) {
  __builtin_amdgcn_global_load_lds((const __attribute__((address_space(1))) void*)g,
                                   (__attribute__((address_space(3))) void*)l, 16, 0, 0);
}

// ---------------- fp32 -> bf16 convert ----------------
__global__ void cvt_all(const float* __restrict__ x, const float* __restrict__ wq,
                        const float* __restrict__ wk, const float* __restrict__ wv,
                        const float* __restrict__ wo, u16* __restrict__ out) {
  const int xn4 = 2097152, wn4 = 262144;
  const int total = xn4 + 4 * wn4;
  int i = blockIdx.x * blockDim.x + threadIdx.x;
  int stride = gridDim.x * blockDim.x;
  for (; i < total; i += stride) {
    const float* src; int off;
    if (i < xn4) { src = x; off = i; }
    else {
      int j = i - xn4; int wsel = j >> 18; off = j & (wn4 - 1);
      src = (wsel == 0) ? wq : (wsel == 1) ? wk : (wsel == 2) ? wv : wo;
    }
    float4 v = ((const float4*)src)[off];
    u16x4 o;
    o.x = f2bf(v.x); o.y = f2bf(v.y); o.z = f2bf(v.z); o.w = f2bf(v.w);
    ((u16x4*)out)[i] = o;
  }
}

// ---------------- fused QKV GEMM ----------------
__global__ __launch_bounds__(256) void gemm_qkv(
    const u16* __restrict__ A, const u16* __restrict__ Wt,
    const float* __restrict__ bq, const float* __restrict__ bk, const float* __restrict__ bv,
    u16* __restrict__ Qo, u16* __restrict__ Ko, u16* __restrict__ Vo, float qscale)
{
  __shared__ u16 As[128 * 32];
  __shared__ u16 Bs[128 * 32];
  const int K = 1024, tiles_n = 24;
  int nwg = 64 * 24;
  int bid = blockIdx.x;
  { int q = nwg >> 3; bid = (bid & 7) * q + (bid >> 3); }
  int tm = bid / tiles_n, tn = bid % tiles_n;
  int tid = threadIdx.x;
  int wid = tid >> 6, lane = tid & 63;
  int wr = wid >> 1, wc = wid & 1;

  f32x4 acc[4][4] = {};
  int a_row = wr * 64 + (lane & 15);
  int b_row = wc * 64 + (lane & 15);
  int frag_k = (lane >> 4) * 8;

  const u16* ga0 = A + (size_t)(tm * 128 + wid * 32 + (lane >> 2)) * K + (lane & 3) * 8;
  const u16* ga1 = ga0 + (size_t)16 * K;
  const u16* gb0 = Wt + (size_t)(tn * 128 + wid * 32 + (lane >> 2)) * K + (lane & 3) * 8;
  const u16* gb1 = gb0 + (size_t)16 * K;
  u16* lA0 = As + wid * 1024;
  u16* lA1 = As + wid * 1024 + 512;
  u16* lB0 = Bs + wid * 1024;
  u16* lB1 = Bs + wid * 1024 + 512;

  for (int kt = 0; kt < K; kt += 32) {
    gll16(ga0 + kt, lA0);
    gll16(ga1 + kt, lA1);
    gll16(gb0 + kt, lB0);
    gll16(gb1 + kt, lB1);
    __syncthreads();
    bf16x8 af[4], bfr[4];
#pragma unroll
    for (int i = 0; i < 4; i++)
      af[i] = *(const bf16x8*)(As + (a_row + i * 16) * 32 + frag_k);
#pragma unroll
    for (int i = 0; i < 4; i++)
      bfr[i] = *(const bf16x8*)(Bs + (b_row + i * 16) * 32 + frag_k);
#pragma unroll
    for (int i = 0; i < 4; i++)
#pragma unroll
      for (int j = 0; j < 4; j++)
        acc[i][j] = __builtin_amdgcn_mfma_f32_16x16x32_bf16(af[i], bfr[j], acc[i][j], 0, 0, 0);
    __syncthreads();
  }

#pragma unroll
  for (int i = 0; i < 4; i++) {
#pragma unroll
    for (int j = 0; j < 4; j++) {
      int col = tn * 128 + wc * 64 + j * 16 + (lane & 15);
      int wsel = col >> 10, c10 = col & 1023;
      int h = c10 >> 6, hd = c10 & 63;
      float bvv = (wsel == 0 ? bq : wsel == 1 ? bk : bv)[c10];
      int row0 = tm * 128 + wr * 64 + i * 16 + (lane >> 4) * 4;
      int b_ = row0 >> 11, s0 = row0 & 2047;
      if (wsel == 2) {
        u16x4 o;
#pragma unroll
        for (int r = 0; r < 4; r++) o[r] = f2bf(acc[i][j][r] + bvv);
        *(u16x4*)&Vo[((size_t)(b_ * 16 + h) * 64 + hd) * 2048 + s0] = o;
      } else {
        u16* dst = (wsel == 0) ? Qo : Ko;
        float sc = (wsel == 0) ? qscale : 1.0f;
#pragma unroll
        for (int r = 0; r < 4; r++)
          dst[(((size_t)(b_ * 16 + h) * 2048 + (s0 + r)) << 6) + hd] = f2bf((acc[i][j][r] + bvv) * sc);
      }
    }
  }
}

// ---------------- out GEMM: fp32 [M,N] ----------------
__global__ __launch_bounds__(256) void gemm_out(
    const u16* __restrict__ A, const u16* __restrict__ Bt,
    const float* __restrict__ bias, float* __restrict__ out,
    int M, int N, int K)
{
  __shared__ u16 As[128 * 32];
  __shared__ u16 Bs[128 * 32];
  int tiles_n = N >> 7;
  int nwg = (M >> 7) * tiles_n;
  int bid = blockIdx.x;
  { int q = nwg >> 3; bid = (bid & 7) * q + (bid >> 3); }
  int tm = bid / tiles_n, tn = bid % tiles_n;
  int tid = threadIdx.x;
  int wid = tid >> 6, lane = tid & 63;
  int wr = wid >> 1, wc = wid & 1;

  f32x4 acc[4][4] = {};
  int a_row = wr * 64 + (lane & 15);
  int b_row = wc * 64 + (lane & 15);
  int frag_k = (lane >> 4) * 8;

  const u16* ga0 = A + (size_t)(tm * 128 + wid * 32 + (lane >> 2)) * K + (lane & 3) * 8;
  const u16* ga1 = ga0 + (size_t)16 * K;
  const u16* gb0 = Bt + (size_t)(tn * 128 + wid * 32 + (lane >> 2)) * K + (lane & 3) * 8;
  const u16* gb1 = gb0 + (size_t)16 * K;
  u16* lA0 = As + wid * 1024;
  u16* lA1 = As + wid * 1024 + 512;
  u16* lB0 = Bs + wid * 1024;
  u16* lB1 = Bs + wid * 1024 + 512;

  for (int kt = 0; kt < K; kt += 32) {
    gll16(ga0 + kt, lA0);
    gll16(ga1 + kt, lA1);
    gll16(gb0 + kt, lB0);
    gll16(gb1 + kt, lB1);
    __syncthreads();
    bf16x8 af[4], bfr[4];
#pragma unroll
    for (int i = 0; i < 4; i++)
      af[i] = *(const bf16x8*)(As + (a_row + i * 16) * 32 + frag_k);
#pragma unroll
    for (int i = 0; i < 4; i++)
      bfr[i] = *(const bf16x8*)(Bs + (b_row + i * 16) * 32 + frag_k);
#pragma unroll
    for (int i = 0; i < 4; i++)
#pragma unroll
      for (int j = 0; j < 4; j++)
        acc[i][j] = __builtin_amdgcn_mfma_f32_16x16x32_bf16(af[i], bfr[j], acc[i][j], 0, 0, 0);
    __syncthreads();
  }

#pragma unroll
  for (int i = 0; i < 4; i++)
#pragma unroll
    for (int j = 0; j < 4; j++) {
      int col = tn * 128 + wc * 64 + j * 16 + (lane & 15);
      float bv = bias[col];
#pragma unroll
      for (int r = 0; r < 4; r++) {
        int row = tm * 128 + wr * 64 + i * 16 + (lane >> 4) * 4 + r;
        out[(size_t)row * N + col] = acc[i][j][r] + bv;
      }
    }
}

// ---------------- fused attention (round-6 structure; pass-1 4x unrolled) ----------------
// grid 1024 (bh x qt128), 512 threads = 8 waves.
// LDS: Ks[8] 8KB buffers. Pass1: two ping-pong groups of 4 K-tiles (1 barrier-pair / 256 rows).
// Pass2: K in Ks[0..3], V in Ks[4..7], dist-3 counted-vmcnt pipeline (proven r6).
__global__ __launch_bounds__(512, 4) void attn_fused(
    const u16* __restrict__ Qb, const u16* __restrict__ Kb,
    const u16* __restrict__ Vtb, float* __restrict__ attn_out,
    u16* __restrict__ ctxb)
{
  __shared__ u16 Ks[8][4096];   // 64KB
  __shared__ u16 Ps[8192];      // 16KB

  int bid = blockIdx.x;
  int swz = (bid & 7) * 128 + (bid >> 3);   // 8 bh per XCD
  int bh = swz >> 4, qt = swz & 15;
  int tid = threadIdx.x, w = tid >> 6, lane = tid & 63;
  int g = lane >> 4, l15 = lane & 15;

  const u16* Qg = Qb + ((size_t)bh * 2048 + qt * 128) * 64;
  const u16* Kg = Kb + (size_t)bh * 2048 * 64;
  const u16* Vg = Vtb + (size_t)bh * 64 * 2048;
  float* Ag = attn_out + ((size_t)bh * 2048 + qt * 128) * 2048;

  int qloc = w * 16 + l15;
  bf16x8 aq0 = *(const bf16x8*)(Qg + (size_t)qloc * 64 + g * 8);
  bf16x8 aq1 = *(const bf16x8*)(Qg + (size_t)qloc * 64 + 32 + g * 8);

  int srow = w * 8 + (lane >> 3);
  int schunk = (lane & 7) ^ (lane >> 3);
  const u16* Ksrc = Kg + (size_t)srow * 64 + schunk * 8;
  const u16* Vsrc = Vg + (size_t)srow * 2048 + schunk * 8;

  // ---------------- pass 1: row sums, 8 outer iters x 4 tiles ----------------
  float ls0 = 0.f, ls1 = 0.f, ls2 = 0.f, ls3 = 0.f;
#pragma unroll
  for (int t = 0; t < 4; t++)
    gll16(Ksrc + (size_t)t * 4096, (char*)Ks[t] + w * 1024);
  for (int o = 0; o < 8; ++o) {
    int gb = (o & 1) << 2;
    if (o < 7) {
#pragma unroll
      for (int t = 0; t < 4; t++)
        gll16(Ksrc + (size_t)(4 * o + 4 + t) * 4096, (char*)Ks[(gb ^ 4) + t] + w * 1024);
      asm volatile("s_waitcnt vmcnt(4)" ::: "memory");
    } else {
      asm volatile("s_waitcnt vmcnt(0)" ::: "memory");
    }
    __builtin_amdgcn_s_barrier();
#pragma unroll
    for (int t4 = 0; t4 < 4; t4++) {
      const char* Kbase = (const char*)Ks[gb + t4];
      f32x4 s[4] = {};
      __builtin_amdgcn_s_setprio(1);
#pragma unroll
      for (int t = 0; t < 4; t++) {
        int kr = t * 16 + l15;
        int x = (kr & 7) << 4;
        bf16x8 k0 = *(const bf16x8*)(Kbase + kr * 128 + ((g * 16) ^ x));
        bf16x8 k1 = *(const bf16x8*)(Kbase + kr * 128 + ((64 + g * 16) ^ x));
        s[t] = __builtin_amdgcn_mfma_f32_16x16x32_bf16(k0, aq0, s[t], 0, 0, 0);
        s[t] = __builtin_amdgcn_mfma_f32_16x16x32_bf16(k1, aq1, s[t], 0, 0, 0);
      }
      __builtin_amdgcn_s_setprio(0);
#pragma unroll
      for (int r = 0; r < 4; r++) {
        ls0 += EXP2(s[0][r]); ls1 += EXP2(s[1][r]);
        ls2 += EXP2(s[2][r]); ls3 += EXP2(s[3][r]);
      }
    }
    asm volatile("" ::: "memory");
    __builtin_amdgcn_s_barrier();
  }
  float lsum = (ls0 + ls1) + (ls2 + ls3);
  lsum += __shfl_xor(lsum, 16);
  lsum += __shfl_xor(lsum, 32);
  float lr2 = -LOG2(lsum);

  // ---------------- pass 2: attn write (nt float4) + PV (round-6 proven) ----------------
  f32x4 ctx[4] = {};
  int xq = (qloc & 7) << 4;
  char* Pb = (char*)Ps + qloc * 128;
#pragma unroll
  for (int p = 0; p < 3; p++) {
    gll16(Ksrc + (size_t)p * 4096, (char*)Ks[p] + w * 1024);
    gll16(Vsrc + (size_t)p * 64,  (char*)Ks[4 + p] + w * 1024);
  }
  for (int it = 0; it < 32; ++it) {
    int nx = (it + 3) & 31;
    int nb = (it + 3) & 3;
    gll16(Ksrc + (size_t)nx * 4096, (char*)Ks[nb] + w * 1024);
    gll16(Vsrc + (size_t)nx * 64,  (char*)Ks[4 + nb] + w * 1024);
    if (it == 0)      asm volatile("s_waitcnt vmcnt(6)" ::: "memory");
    else if (it == 1) asm volatile("s_waitcnt vmcnt(10)" ::: "memory");
    else if (it == 2) asm volatile("s_waitcnt vmcnt(14)" ::: "memory");
    else              asm volatile("s_waitcnt vmcnt(18)" ::: "memory");
    __builtin_amdgcn_s_barrier();
    f32x4 s[4] = {};
    const char* Kbase = (const char*)Ks[it & 3];
    const char* Vbase = (const char*)Ks[4 + (it & 3)];
    __builtin_amdgcn_s_setprio(1);
#pragma unroll
    for (int t = 0; t < 4; t++) {
      int kr = t * 16 + l15;
      int x = (kr & 7) << 4;
      bf16x8 k0 = *(const bf16x8*)(Kbase + kr * 128 + ((g * 16) ^ x));
      bf16x8 k1 = *(const bf16x8*)(Kbase + kr * 128 + ((64 + g * 16) ^ x));
      s[t] = __builtin_amdgcn_mfma_f32_16x16x32_bf16(k0, aq0, s[t], 0, 0, 0);
      s[t] = __builtin_amdgcn_mfma_f32_16x16x32_bf16(k1, aq1, s[t], 0, 0, 0);
    }
    __builtin_amdgcn_s_setprio(0);
    float* Arow = Ag + (size_t)qloc * 2048 + it * 64 + g * 4;
#pragma unroll
    for (int t = 0; t < 4; t++) {
      f32x4 p;
#pragma unroll
      for (int r = 0; r < 4; r++) p[r] = EXP2(s[t][r] + lr2);
      __builtin_nontemporal_store(p, (f32x4*)(Arow + t * 16));
      uint2 pk;
      pk.x = cvtpk(p[0], p[1]);
      pk.y = cvtpk(p[2], p[3]);
      *(uint2*)(Pb + ((t * 32 + g * 8) ^ xq)) = pk;
    }
    __builtin_amdgcn_s_setprio(1);
#pragma unroll
    for (int kk = 0; kk < 2; kk++) {
      bf16x8 ap = *(const bf16x8*)(Pb + ((kk * 64 + g * 16) ^ xq));
#pragma unroll
      for (int t = 0; t < 4; t++) {
        int dr = t * 16 + l15;
        bf16x8 bv = *(const bf16x8*)(Vbase + dr * 128 + ((kk * 64 + g * 16) ^ ((dr & 7) << 4)));
        ctx[t] = __builtin_amdgcn_mfma_f32_16x16x32_bf16(ap, bv, ctx[t], 0, 0, 0);
      }
    }
    __builtin_amdgcn_s_setprio(0);
    asm volatile("" ::: "memory");
    __builtin_amdgcn_s_barrier();
  }

  int b_ = bh >> 4, h = bh & 15;
#pragma unroll
  for (int t = 0; t < 4; t++)
#pragma unroll
    for (int r = 0; r < 4; r++) {
      int qg = qt * 128 + w * 16 + g * 4 + r;
      int col = h * 64 + t * 16 + l15;
      ctxb[((size_t)b_ * 2048 + qg) * 1024 + col] = f2bf(ctx[t][r]);
    }
}

// ---------------- launch ----------------
extern "C" void kernel_launch(void* const* d_in, const int* in_sizes, int n_in,
                              void* d_out, int out_size, void* d_ws, size_t ws_size,
                              hipStream_t stream) {
  const float* x  = (const float*)d_in[0];
  const float* Wq = (const float*)d_in[1];
  const float* bq = (const float*)d_in[2];
  const float* Wk = (const float*)d_in[3];
  const float* bk = (const float*)d_in[4];
  const float* Wv = (const float*)d_in[5];
  const float* bv = (const float*)d_in[6];
  const float* Wo = (const float*)d_in[7];
  const float* bo = (const float*)d_in[8];

  u16* xb   = (u16*)d_ws;
  u16* Wqb  = xb + (size_t)Mm * Dd;
  u16* Wkb  = Wqb + (size_t)Dd * Dd;
  u16* Wvb  = Wkb + (size_t)Dd * Dd;
  u16* Wob  = Wvb + (size_t)Dd * Dd;
  u16* Qb   = Wob + (size_t)Dd * Dd;
  u16* Kbuf = Qb + (size_t)Mm * Dd;
  u16* Vtb  = Kbuf + (size_t)Mm * Dd;
  u16* ctxb = Vtb + (size_t)Mm * Dd;

  float* out_f = (float*)d_out;
  float* attn_o = out_f + (size_t)Mm * Dd;

  cvt_all<<<2048, 256, 0, stream>>>(x, Wq, Wk, Wv, Wo, xb);

  const float qscale = 0.125f * 1.44269504088896340736f;  // 1/sqrt(64) * log2(e)
  gemm_qkv<<<1536, 256, 0, stream>>>(xb, Wqb, bq, bk, bv, Qb, Kbuf, Vtb, qscale);
  attn_fused<<<1024, 512, 0, stream>>>(Qb, Kbuf, Vtb, attn_o, ctxb);
  gemm_out<<<512, 256, 0, stream>>>(ctxb, Wob, bo, out_f, Mm, Dd, Dd);
}